// Round 10
// baseline (155.334 us; speedup 1.0000x reference)
//
#include <hip/hip_runtime.h>
#include <math.h>

#define BB 64
#define LL 512
#define DD 512
#define CC 50
#define NC 100
#define NCP 112

// ws byte layout:
//   0: loss f32   4: cnt f32   8: done counter (int)
//   64:      scomb f32 [64][112]                   (28672 B)
//   28736:   span partials bf16 [8 seg][64 b][512] (524288 B)
//   553024:  Wbot bf16 [112][512] (rows 100..111 unused)
//   667712:  Bpack bf16 fragment-packed [112 frag][64 ln][8] (114688 B)
#define WSB_LOSS  0
#define WSB_CNT   4
#define WSB_DONE  8
#define WSB_SCOMB 64
#define WSB_PART  28736
#define WSB_WBOT  553024
#define WSB_BPACK 667712

typedef __attribute__((ext_vector_type(8))) short bf16x8;
typedef __attribute__((ext_vector_type(4))) float f32x4;

static __device__ __forceinline__ unsigned short f2bf(float x) {
    unsigned int u = __float_as_uint(x);
    u += 0x7FFFu + ((u >> 16) & 1u);          // RNE
    return (unsigned short)(u >> 16);
}
static __device__ __forceinline__ float bf2f(unsigned short h) {
    return __uint_as_float(((unsigned int)h) << 16);
}
// pack two f32 -> bf16x2 (truncate): low short = hi16(a), high = hi16(b)
static __device__ __forceinline__ unsigned int pk2bf(float a, float b) {
    return __builtin_amdgcn_perm(__float_as_uint(b), __float_as_uint(a), 0x07060302u);
}
static __device__ __forceinline__ void gl2lds16(const void* g, void* l) {
    __builtin_amdgcn_global_load_lds(
        (const __attribute__((address_space(1))) unsigned int*)g,
        (__attribute__((address_space(3))) unsigned int*)l, 16, 0, 0);
}

// ---------------------------------------------------------------------------
// k_prep (unchanged): span partials / Wbot transpose / Bpack build.
// ---------------------------------------------------------------------------
__global__ __launch_bounds__(256) void k_prep(
    const float* __restrict__ tv, const int* __restrict__ sbj_bound,
    const float* __restrict__ Wst, const float* __restrict__ Wen,
    char* __restrict__ wsb)
{
    __shared__ float sh[128 * 53];
    const int t = threadIdx.x;
    const int blk = blockIdx.x;

    if (blk < 512) {
        const int b = blk >> 3, seg = blk & 7;
        const int start = sbj_bound[2 * b], end = sbj_bound[2 * b + 1];
        int r0 = seg * 64;      if (r0 < start) r0 = start;
        int r1 = seg * 64 + 63; if (r1 > end)   r1 = end;
        const int c4 = t & 127, par = t >> 7;
        const float* bp = tv + (size_t)b * LL * DD + c4 * 4;
        float4 a0 = {0, 0, 0, 0}, a1 = {0, 0, 0, 0};
        int r = r0 + par;
        for (; r + 2 <= r1; r += 4) {
            float4 v0 = *(const float4*)(bp + (size_t)r * DD);
            float4 v1 = *(const float4*)(bp + (size_t)(r + 2) * DD);
            a0.x += v0.x; a0.y += v0.y; a0.z += v0.z; a0.w += v0.w;
            a1.x += v1.x; a1.y += v1.y; a1.z += v1.z; a1.w += v1.w;
        }
        for (; r <= r1; r += 2) {
            float4 v0 = *(const float4*)(bp + (size_t)r * DD);
            a0.x += v0.x; a0.y += v0.y; a0.z += v0.z; a0.w += v0.w;
        }
        float4* buf = (float4*)sh;
        float4 acc = {a0.x + a1.x, a0.y + a1.y, a0.z + a1.z, a0.w + a1.w};
        buf[t] = acc;
        __syncthreads();
        if (t < 128) {
            float4 x = buf[t], y = buf[t + 128];
            unsigned short* part = (unsigned short*)(wsb + WSB_PART);
            ushort4 o;
            o.x = f2bf(x.x + y.x); o.y = f2bf(x.y + y.y);
            o.z = f2bf(x.z + y.z); o.w = f2bf(x.w + y.w);
            *(ushort4*)(part + ((size_t)(seg * BB + b)) * DD + t * 4) = o;
        }
    } else if (blk < 520) {
        const int bi = blk - 512;              // 0..7
        const int mat = bi >> 2;               // 0: W_start, 1: W_end
        const int cj = bi & 3;                 // 128-row chunk of k in [512,1024)
        const float* W = mat ? Wen : Wst;
        const int kbase = 512 + cj * 128;
        const float* src = W + (size_t)kbase * CC;
#pragma unroll
        for (int i = 0; i < 25; i++) {
            int idx = t + i * 256;             // [0,6400)
            sh[idx] = src[idx];
        }
        __syncthreads();
        unsigned short* outp = (unsigned short*)(wsb + WSB_WBOT);
        const int kout = cj * 128;
#pragma unroll
        for (int i = 0; i < 25; i++) {
            int idx = t + i * 256;             // 50 n x 128 kl
            int n = idx >> 7, kl = idx & 127;
            outp[((size_t)(mat * CC + n)) * DD + kout + kl] = f2bf(sh[kl * 50 + n]);
        }
        if (bi == 0 && t == 0) {
            *(float*)(wsb + WSB_LOSS) = 0.0f;
            *(float*)(wsb + WSB_CNT)  = 0.0f;
            *(int*)(wsb + WSB_DONE)   = 0;
        }
    } else {
        const int bi = blk - 520;              // 0..15
        const int ln = t & 63, jj = t >> 6;    // jj 0..3
        const int tc = ln & 15, quad = ln >> 4;
        const int j0 = jj * 2;
        unsigned int* bp = (unsigned int*)(wsb + WSB_BPACK);
#pragma unroll
        for (int q = 0; q < 7; q++) {
            const int fid = bi * 7 + q;        // 0..111
            const int u = fid % 7, s = fid / 7;
            const int cc = u * 16 + tc;
            const int k0 = s * 32 + quad * 8 + j0;
            float a = 0.f, bb = 0.f;
            if (cc < CC) {
                a  = Wst[(size_t)k0 * CC + cc];
                bb = Wst[(size_t)(k0 + 1) * CC + cc];
            } else if (cc < NC) {
                a  = Wen[(size_t)k0 * CC + cc - CC];
                bb = Wen[(size_t)(k0 + 1) * CC + cc - CC];
            }
            bp[fid * 256 + ln * 4 + jj] =
                (unsigned int)f2bf(a) | ((unsigned int)f2bf(bb) << 16);
        }
    }
}

// ---------------------------------------------------------------------------
// k_scomb (unchanged): combine seg-partials -> sbj, sbj @ Wbot^T -> scomb.
// ---------------------------------------------------------------------------
#define SST 520
__global__ __launch_bounds__(256) void k_scomb(
    const int* __restrict__ sbj_bound,
    const float* __restrict__ bst, const float* __restrict__ ben,
    char* __restrict__ wsb)
{
    __shared__ __align__(16) unsigned short sbjb[16 * SST];
    const int t = threadIdx.x;
    const int g = blockIdx.x;
    const unsigned short* part = (const unsigned short*)(wsb + WSB_PART);

#pragma unroll
    for (int i = 0; i < 8; i++) {
        int idx = t + i * 256;                 // [0, 2048)
        int bo = idx >> 7, d4 = idx & 127;
        int b = g * 16 + bo;
        float inv = 1.0f / (float)(sbj_bound[2 * b + 1] - sbj_bound[2 * b] + 1);
        float sx = 0.f, sy = 0.f, sz = 0.f, sw = 0.f;
#pragma unroll
        for (int seg = 0; seg < 8; seg++) {
            ushort4 v = *(const ushort4*)(part + ((size_t)(seg * BB + b)) * DD + d4 * 4);
            sx += bf2f(v.x); sy += bf2f(v.y); sz += bf2f(v.z); sw += bf2f(v.w);
        }
        ushort4 o;
        o.x = f2bf(sx * inv); o.y = f2bf(sy * inv);
        o.z = f2bf(sz * inv); o.w = f2bf(sw * inv);
        *(ushort4*)(sbjb + bo * SST + d4 * 4) = o;
    }
    __syncthreads();

    const int wv = t >> 6, ln = t & 63, tc = ln & 15, quad = ln >> 4;
    const unsigned short* wbot = (const unsigned short*)(wsb + WSB_WBOT);
    float* scomb = (float*)(wsb + WSB_SCOMB);
    const unsigned short* Af = sbjb + tc * SST + quad * 8;
    const int nu = (wv < 3) ? 2 : 1;
    for (int j = 0; j < nu; j++) {
        const int u = wv * 2 + j;
        f32x4 acc = (f32x4)(0.0f);
        const unsigned short* Bf = wbot + (size_t)(u * 16 + tc) * DD + quad * 8;
#pragma unroll
        for (int kk = 0; kk < DD; kk += 32) {
            bf16x8 af = *(const bf16x8*)(Af + kk);
            bf16x8 bf = *(const bf16x8*)(Bf + kk);
            acc = __builtin_amdgcn_mfma_f32_16x16x32_bf16(af, bf, acc, 0, 0, 0);
        }
        const int cc = u * 16 + tc;
        const float bias = (cc < CC) ? bst[cc] : ((cc < NC) ? ben[cc - CC] : 0.0f);
#pragma unroll
        for (int i = 0; i < 4; i++) {
            int b = g * 16 + quad * 4 + i;
            scomb[b * NCP + cc] = acc[i] + bias;
        }
    }
}

// ---------------------------------------------------------------------------
// k_main: 512 blocks x 448 thr (7 waves). N-SPLIT: wave u owns 16 cols with
// B-frags in REGISTERS (64 VGPR, loaded once from L2-hot Bpack). LDS = only a
// 2x8KB A double-buffer (64 rows x 32 k f32, gl2lds, XOR-swizzled) + logits.
// ~29KB LDS + <=128 VGPR -> 2 blocks/CU = 14 waves, anti-phase overlap.
// 1-barrier K-loop. Epilogue: logits via LDS, 128 threads do 50-col softmax.
// ---------------------------------------------------------------------------
__global__ __launch_bounds__(448, 4) void k_main(
    const float* __restrict__ tv,
    const int* __restrict__ mask,
    const int* __restrict__ obj_s, const int* __restrict__ obj_e,
    char* __restrict__ wsb, float* __restrict__ out)
{
    __shared__ __align__(16) float smem[64 * 113];   // staging uses [0,4096)
    __shared__ float red[16];
    const int t = threadIdx.x, wv = t >> 6, ln = t & 63;
    const int tc = ln & 15, quad = ln >> 4;
    const int u = wv;                       // wave's col-frag (0..6)
    const int m0 = blockIdx.x * 64;
    const int b = blockIdx.x >> 3;

    // ---- B-frags into registers: 16 x dwordx4, coalesced, L2/L3-hot ----
    bf16x8 breg[16];
    {
        const char* gB = wsb + WSB_BPACK;
#pragma unroll
        for (int s = 0; s < 16; s++)
            breg[s] = *(const bf16x8*)(gB + ((size_t)((s * 7 + u) * 64 + ln)) * 16);
    }

    // ---- A staging: tile s = 64 rows x 32 k f32 (8KB), slot gs = g^(r&7) ----
    // lane ln covers slot j*64+ln: r = j*8 + (ln>>3), gs = ln&7, g = gs^(r&7)
    const int arow = ln >> 3;
    const int agr  = (ln & 7) ^ (arow & 7);
    // stage tile s into half (s&1)
    // (lambda-free: macro-ish inline below)

    {   // prologue: stage tile 0
        const float* gbase = tv + (size_t)m0 * DD;
#pragma unroll
        for (int j = wv; j < 8; j += 7) {
            const float* g = gbase + (size_t)(j * 8 + arow) * DD + agr * 4;
            gl2lds16(g, (char*)smem + (size_t)j * 1024);
        }
    }

    f32x4 acc[4];
#pragma unroll
    for (int mf = 0; mf < 4; mf++) acc[mf] = (f32x4)(0.0f);
    const int g0 = (quad * 2) ^ (tc & 7);
    const int g1 = (quad * 2 + 1) ^ (tc & 7);

    for (int s = 0; s < 16; s++) {
        __syncthreads();                    // tile s staged; buf (s+1)&1 free
        if (s < 15) {                       // stage tile s+1
            const float* gbase = tv + (size_t)m0 * DD + (s + 1) * 32;
            char* dst = (char*)smem + ((s + 1) & 1) * 8192;
#pragma unroll
            for (int j = wv; j < 8; j += 7) {
                const float* g = gbase + (size_t)(j * 8 + arow) * DD + agr * 4;
                gl2lds16(g, dst + (size_t)j * 1024);
            }
        }
        const float* Ab = smem + (s & 1) * 2048;
#pragma unroll
        for (int mf = 0; mf < 4; mf++) {
            const int r = mf * 16 + tc;
            float4 v0 = *(const float4*)(Ab + r * 32 + g0 * 4);
            float4 v1 = *(const float4*)(Ab + r * 32 + g1 * 4);
            union { unsigned int u32[4]; bf16x8 v; } af;
            af.u32[0] = pk2bf(v0.x, v0.y); af.u32[1] = pk2bf(v0.z, v0.w);
            af.u32[2] = pk2bf(v1.x, v1.y); af.u32[3] = pk2bf(v1.z, v1.w);
            acc[mf] = __builtin_amdgcn_mfma_f32_16x16x32_bf16(af.v, breg[s], acc[mf], 0, 0, 0);
        }
    }
    __syncthreads();                        // all compute done; reuse smem

    // ---- gather logits to LDS: Lg[row][cc], stride 113 ----
    {
        const float* scomb = (const float*)(wsb + WSB_SCOMB);
        const float scv = scomb[b * NCP + u * 16 + tc];
#pragma unroll
        for (int mf = 0; mf < 4; mf++) {
#pragma unroll
            for (int i = 0; i < 4; i++) {
                const int row = mf * 16 + quad * 4 + i;
                smem[row * 113 + u * 16 + tc] = acc[mf][i] + scv;
            }
        }
    }
    __syncthreads();

    // ---- 128 threads: (row, head) softmax over 50 cols + NLL ----
    float loss_local = 0.0f, cnt_local = 0.0f;
    if (t < 128) {
        const int row = t >> 1, head = t & 1;
        const int l = (m0 + row) & (LL - 1);
        const int lab = head ? obj_e[b * LL + l] : obj_s[b * LL + l];
        const int mk  = mask[b * LL + l];
        const float* Lr = smem + row * 113 + head * CC;
        float mx = Lr[0];
#pragma unroll 5
        for (int c = 1; c < CC; c++) mx = fmaxf(mx, Lr[c]);
        float es = 0.0f;
#pragma unroll 5
        for (int c = 0; c < CC; c++) es = __builtin_fmaf(expf(Lr[c] - mx), 1.0f, es);
        const float nll = mx + logf(es) - Lr[lab];
        if (mk) { loss_local = nll; cnt_local = head ? 0.0f : 1.0f; }
    }
#pragma unroll
    for (int off = 1; off < 64; off <<= 1) {
        loss_local += __shfl_xor(loss_local, off);
        cnt_local  += __shfl_xor(cnt_local, off);
    }
    if (ln == 0) { red[wv * 2] = loss_local; red[wv * 2 + 1] = cnt_local; }
    __syncthreads();
    if (t == 0) {
        float Ls = 0.f, Cs = 0.f;
#pragma unroll
        for (int w = 0; w < 7; w++) { Ls += red[w * 2]; Cs += red[w * 2 + 1]; }
        float* wsf = (float*)wsb;
        atomicAdd(&wsf[0], Ls);
        atomicAdd(&wsf[1], Cs);
        __threadfence();
        int old = atomicAdd((int*)(wsb + WSB_DONE), 1);
        if (old == (int)gridDim.x - 1) {
            float L = atomicAdd(&wsf[0], 0.0f);   // coherent read
            float C = atomicAdd(&wsf[1], 0.0f);
            out[0] = L / C;
        }
    }
}

extern "C" void kernel_launch(void* const* d_in, const int* in_sizes, int n_in,
                              void* d_out, int out_size, void* d_ws, size_t ws_size,
                              hipStream_t stream) {
    const float* tv   = (const float*)d_in[0];
    const int*   mask = (const int*)d_in[1];
    const int*   sbj  = (const int*)d_in[2];
    const int*   objs = (const int*)d_in[3];
    const int*   obje = (const int*)d_in[4];
    const float* Wst  = (const float*)d_in[5];
    const float* bst  = (const float*)d_in[6];
    const float* Wen  = (const float*)d_in[7];
    const float* ben  = (const float*)d_in[8];
    float* out = (float*)d_out;
    char*  wsb = (char*)d_ws;

    k_prep<<<536, 256, 0, stream>>>(tv, sbj, Wst, Wen, wsb);
    k_scomb<<<4, 256, 0, stream>>>(sbj, bst, ben, wsb);
    k_main<<<512, 448, 0, stream>>>(tv, mask, objs, obje, wsb, out);
}